// Round 4
// baseline (210.711 us; speedup 1.0000x reference)
//
#include <hip/hip_runtime.h>
#include <hip/hip_bf16.h>

#define BB 64
#define SS 2048
#define DD 512
#define MTOT (BB * SS)          // 131072 rows

typedef __attribute__((ext_vector_type(8))) short short8;            // 8 bf16
typedef __attribute__((ext_vector_type(8))) unsigned short ushort8;
typedef __attribute__((ext_vector_type(4))) float f32x4;

// RNE fp32->bf16 via compiler (fuses pairs into v_cvt_pk_bf16_f32 — m240)
__device__ __forceinline__ unsigned short f2bf(float f){
  __hip_bfloat16 h = __float2bfloat16(f);
  return *reinterpret_cast<unsigned short*>(&h);
}

__device__ __forceinline__ float bf2f(unsigned short u){
  union { unsigned int i; float f; } a; a.i = ((unsigned int)u) << 16;
  return a.f;
}

__device__ __forceinline__ ushort8 pack8(float4 a, float4 b){
  ushort8 u;
  u[0]=f2bf(a.x); u[1]=f2bf(a.y); u[2]=f2bf(a.z); u[3]=f2bf(a.w);
  u[4]=f2bf(b.x); u[5]=f2bf(b.y); u[6]=f2bf(b.z); u[7]=f2bf(b.w);
  return u;
}

__device__ __forceinline__ void gload_lds16(const unsigned short* g, unsigned short* l){
  __builtin_amdgcn_global_load_lds(
      (const __attribute__((address_space(1))) unsigned int*)g,
      (__attribute__((address_space(3))) unsigned int*)l, 16, 0, 0);
}

// ---- kernel 1: W1 fp32 -> bf16, PRE-SWIZZLED per-step tile layout ----
// granule (s,g): W1 row e=(g&511)^kc (kc=g>>9), k-elems [s*32+kc*8, +8).
__global__ void cvt_w1_kernel(const float* __restrict__ W1, unsigned short* __restrict__ W1s){
  int i = blockIdx.x * blockDim.x + threadIdx.x;   // 32768 = 16 steps * 2048 granules
  int s  = i >> 11;
  int g  = i & 2047;
  int kc = g >> 9;
  int e  = (g & 511) ^ kc;
  const float* src = W1 + (size_t)e * DD + s * 32 + kc * 8;
  float4 f0 = *(const float4*)src;
  float4 f1 = *(const float4*)(src + 4);
  *(ushort8*)(W1s + (size_t)i * 8) = pack8(f0, f1);
}

// ---- kernel 2: scores + bf16-x emission ----
// BM=64, BN=512 (full e), BK=32, 16 steps. 512 thr / 8 waves; per-wave 64x64
// tile (acc[4][4]). A reg-staged (fp32->bf16 cvt_pk) + optional bf16-x store;
// B via global_load_lds from pre-swizzled W1s. Double-buffered 72KB LDS.
__launch_bounds__(512, 4)
__global__ void scores_kernel(const float* __restrict__ x,
                              const unsigned short* __restrict__ W1s,
                              const float* __restrict__ b1,
                              const float* __restrict__ w2,
                              float* __restrict__ scorep,
                              unsigned short* __restrict__ xbf){
  __shared__ __align__(16) unsigned short lds[2][18432];   // 2 x 36 KB

  const int t    = threadIdx.x;
  const int lane = t & 63;
  const int wid  = t >> 6;
  const int m0   = blockIdx.x * 64;
  const int arow = lane & 15;
  const int kgrp = lane >> 4;

  f32x4 acc[4][4];
  #pragma unroll
  for (int mt = 0; mt < 4; ++mt)
    #pragma unroll
    for (int et = 0; et < 4; ++et)
      acc[mt][et] = (f32x4){0.f, 0.f, 0.f, 0.f};

  // A staging map (threads < 256): row = t>>2 (0..63), kc = t&3
  const int srow = t >> 2;
  const int skc  = t & 3;
  const float* asrc0 = x + (size_t)(m0 + srow) * DD + skc * 8;
  unsigned short* xdst0 = xbf ? xbf + (size_t)(m0 + srow) * DD + skc * 8 : nullptr;
  const int awoff = ((skc << 6) + (srow ^ skc)) << 4;   // swizzled granule byte off

  // B staging: wave wid issues 4 gload_lds; source linear in pre-swizzled W1s
  const unsigned short* bsrc0 = W1s + ((size_t)((wid << 2) << 6) + lane) * 8;

  // ---- prologue: stage tile 0 (A global loads first: counted-vmcnt friendly) ----
  float4 pf0, pf1;
  if (t < 256){
    pf0 = *(const float4*)asrc0;
    pf1 = *(const float4*)(asrc0 + 4);
  }
  #pragma unroll
  for (int j = 0; j < 4; ++j)
    gload_lds16(bsrc0 + j * 512, &lds[0][2048 + ((wid << 2) + j) * 512]);
  if (t < 256){
    ushort8 u = pack8(pf0, pf1);
    *(ushort8*)((char*)&lds[0][0] + awoff) = u;
    if (xdst0) *(ushort8*)xdst0 = u;
  }
  __syncthreads();

  // ---- main loop: 16 k-steps of 32 ----
  for (int s = 0; s < 16; ++s){
    unsigned short* cur = &lds[s & 1][0];
    unsigned short* nxt = &lds[(s + 1) & 1][0];

    // issue staging for s+1: A first, then B (A-wait becomes vmcnt(4))
    float4 f0, f1;
    if (s < 15){
      if (t < 256){
        const float* as = asrc0 + (s + 1) * 32;
        f0 = *(const float4*)as;
        f1 = *(const float4*)(as + 4);
      }
      const unsigned short* bs = bsrc0 + (size_t)(s + 1) * 16384;
      #pragma unroll
      for (int j = 0; j < 4; ++j)
        gload_lds16(bs + j * 512, nxt + 2048 + ((wid << 2) + j) * 512);
    }

    // fragment reads (swizzled, conflict-minimal)
    short8 af[4], bf[4];
    #pragma unroll
    for (int mt = 0; mt < 4; ++mt){
      int row = mt * 16 + arow;
      af[mt] = *(const short8*)((char*)cur + (((kgrp << 6) + (row ^ kgrp)) << 4));
    }
    #pragma unroll
    for (int et = 0; et < 4; ++et){
      int e = (wid << 6) + (et << 4) + arow;
      bf[et] = *(const short8*)((char*)cur + 4096 + (((kgrp << 9) + (e ^ kgrp)) << 4));
    }

    __builtin_amdgcn_s_setprio(1);
    #pragma unroll
    for (int mt = 0; mt < 4; ++mt)
      #pragma unroll
      for (int et = 0; et < 4; ++et)
        acc[mt][et] = __builtin_amdgcn_mfma_f32_16x16x32_bf16(af[mt], bf[et], acc[mt][et], 0, 0, 0);
    __builtin_amdgcn_s_setprio(0);

    // convert + write A for s+1 (LDS + bf16-x global)
    if (s < 15 && t < 256){
      ushort8 u = pack8(f0, f1);
      *(ushort8*)((char*)nxt + awoff) = u;
      if (xdst0) *(ushort8*)(xdst0 + (s + 1) * 32) = u;
    }
    __syncthreads();
  }

  // ---- epilogue: tanh + dot(w2), reduce over e ----
  float ps[4][4];
  #pragma unroll
  for (int mt = 0; mt < 4; ++mt)
    #pragma unroll
    for (int i = 0; i < 4; ++i) ps[mt][i] = 0.f;

  #pragma unroll
  for (int et = 0; et < 4; ++et){
    int e = (wid << 6) + (et << 4) + arow;     // C/D col = lane&15
    float b1v = b1[e];
    float w2v = w2[e];
    #pragma unroll
    for (int mt = 0; mt < 4; ++mt){
      #pragma unroll
      for (int i = 0; i < 4; ++i){
        float g = acc[mt][et][i] + b1v;
        g = fminf(15.f, fmaxf(-15.f, g));
        float ex = __expf(2.f * g);
        ps[mt][i] += (1.f - 2.f / (ex + 1.f)) * w2v;   // tanh(g)*w2
      }
    }
  }
  #pragma unroll
  for (int mt = 0; mt < 4; ++mt)
    #pragma unroll
    for (int i = 0; i < 4; ++i){
      float v = ps[mt][i];
      v += __shfl_xor(v, 1);
      v += __shfl_xor(v, 2);
      v += __shfl_xor(v, 4);
      v += __shfl_xor(v, 8);
      ps[mt][i] = v;
    }
  float* psum = (float*)&lds[0][0];            // [8][64]; safe after final barrier
  if ((lane & 15) == 0){
    #pragma unroll
    for (int mt = 0; mt < 4; ++mt)
      #pragma unroll
      for (int i = 0; i < 4; ++i)
        psum[wid * 64 + mt * 16 + (lane >> 4) * 4 + i] = ps[mt][i];
  }
  __syncthreads();
  if (t < 64){
    float ssum = 0.f;
    #pragma unroll
    for (int w = 0; w < 8; ++w) ssum += psum[w * 64 + t];
    scorep[m0 + t] = ssum;    // pre-softmax; b2 softmax-invariant
  }
}

// ---- kernel 3: row softmax -> w ----
__global__ void softmax_kernel(const float* __restrict__ scorep, float* __restrict__ wout){
  const int b = blockIdx.x;
  const int t = threadIdx.x;                 // 256
  float v[8];
  #pragma unroll
  for (int i = 0; i < 8; ++i) v[i] = scorep[(size_t)b * SS + t + i * 256];
  float m = v[0];
  #pragma unroll
  for (int i = 1; i < 8; ++i) m = fmaxf(m, v[i]);
  #pragma unroll
  for (int msk = 32; msk >= 1; msk >>= 1) m = fmaxf(m, __shfl_xor(m, msk));
  __shared__ float redm[4], reds[4];
  if ((t & 63) == 0) redm[t >> 6] = m;
  __syncthreads();
  m = fmaxf(fmaxf(redm[0], redm[1]), fmaxf(redm[2], redm[3]));
  float s = 0.f;
  #pragma unroll
  for (int i = 0; i < 8; ++i){ v[i] = __expf(v[i] - m); s += v[i]; }
  #pragma unroll
  for (int msk = 32; msk >= 1; msk >>= 1) s += __shfl_xor(s, msk);
  if ((t & 63) == 0) reds[t >> 6] = s;
  __syncthreads();
  s = reds[0] + reds[1] + reds[2] + reds[3];
  float inv = 1.f / s;
  #pragma unroll
  for (int i = 0; i < 8; ++i) wout[(size_t)b * SS + t + i * 256] = v[i] * inv;
}

// ---- kernel 4a: ctx partials from bf16 x (L3-hot) ----
// grid 512 = 64 b x 8 s-chunks of 256; 512 thr = 8 s-substreams x 64 d-threads
__global__ void ctx_partial_bf16_kernel(const unsigned short* __restrict__ xbf,
                                        const float* __restrict__ wout,
                                        float* __restrict__ ctxp){
  __shared__ float red[8][512];
  const int t   = threadIdx.x;
  const int sub = t >> 6;                    // 0..7 (wave-uniform)
  const int dt  = t & 63;                    // d = dt*8
  const int b   = blockIdx.x >> 3;
  const int sc  = blockIdx.x & 7;
  const unsigned short* xb = xbf + (size_t)b * SS * DD + dt * 8;
  const int s0 = sc * 256 + sub * 32;
  float a[8];
  #pragma unroll
  for (int j = 0; j < 8; ++j) a[j] = 0.f;
  for (int s = s0; s < s0 + 32; ++s){
    float wv = wout[(size_t)b * SS + s];     // wave-uniform
    ushort8 xv = *(const ushort8*)(xb + (size_t)s * DD);
    #pragma unroll
    for (int j = 0; j < 8; ++j) a[j] += wv * bf2f(xv[j]);
  }
  #pragma unroll
  for (int j = 0; j < 8; ++j) red[sub][dt * 8 + j] = a[j];
  __syncthreads();
  if (t < 128){
    float4 o = {0.f, 0.f, 0.f, 0.f};
    #pragma unroll
    for (int sb = 0; sb < 8; ++sb){
      float4 r = *(const float4*)&red[sb][t * 4];
      o.x += r.x; o.y += r.y; o.z += r.z; o.w += r.w;
    }
    *(float4*)&ctxp[((size_t)(b * 8 + sc)) * DD + t * 4] = o;
  }
}

// ---- kernel 4b: fp32 fallback (ws too small for bf16-x) ----
__global__ void ctx_partial_kernel(const float* __restrict__ x, const float* __restrict__ wout,
                                   float* __restrict__ ctxp){
  __shared__ float red[4][512];
  const int t   = threadIdx.x;
  const int sub = t >> 7;
  const int dt  = t & 127;
  const int b   = blockIdx.x >> 3;
  const int sc  = blockIdx.x & 7;
  const float* xb = x + (size_t)b * SS * DD;
  const int s0 = sc * 256 + sub * 64;
  float4 acc = {0.f, 0.f, 0.f, 0.f};
  for (int s = s0; s < s0 + 64; ++s){
    float wv = wout[(size_t)b * SS + s];
    float4 xv = *(const float4*)(xb + (size_t)s * DD + dt * 4);
    acc.x += wv * xv.x; acc.y += wv * xv.y; acc.z += wv * xv.z; acc.w += wv * xv.w;
  }
  *(float4*)&red[sub][dt * 4] = acc;
  __syncthreads();
  if (t < 128){
    float4 r0 = *(const float4*)&red[0][t * 4];
    float4 r1 = *(const float4*)&red[1][t * 4];
    float4 r2 = *(const float4*)&red[2][t * 4];
    float4 r3 = *(const float4*)&red[3][t * 4];
    float4 o = { r0.x+r1.x+r2.x+r3.x, r0.y+r1.y+r2.y+r3.y,
                 r0.z+r1.z+r2.z+r3.z, r0.w+r1.w+r2.w+r3.w };
    *(float4*)&ctxp[((size_t)(b * 8 + sc)) * DD + t * 4] = o;
  }
}

// ---- kernel 5: reduce ctx partials -> d_out ----
__global__ void ctx_reduce_kernel(const float* __restrict__ ctxp, float* __restrict__ ctx){
  int i = blockIdx.x * blockDim.x + threadIdx.x;   // 32768
  int b = i >> 9;
  int d = i & 511;
  float s = 0.f;
  #pragma unroll
  for (int sc = 0; sc < 8; ++sc) s += ctxp[((size_t)(b * 8 + sc)) * DD + d];
  ctx[(size_t)b * DD + d] = s;
}

extern "C" void kernel_launch(void* const* d_in, const int* in_sizes, int n_in,
                              void* d_out, int out_size, void* d_ws, size_t ws_size,
                              hipStream_t stream){
  const float* x  = (const float*)d_in[0];
  const float* W1 = (const float*)d_in[1];
  const float* b1 = (const float*)d_in[2];
  const float* w2 = (const float*)d_in[3];
  // d_in[4] = b2: softmax-invariant, unused.

  float* ctx  = (float*)d_out;                         // [64*512]
  float* wout = (float*)d_out + BB * DD;               // [64*2048]

  // ws layout (bf16-x path):
  //   [0,512K) W1s | [512K,1M) scorep | [1M, 1M+128M) xbf | then ctxp (1M)
  unsigned short* W1s = (unsigned short*)d_ws;
  float* scorep = (float*)((char*)d_ws + (512u << 10));
  const size_t xbf_bytes = (size_t)MTOT * DD * 2;      // 128 MB
  const size_t need = (1u << 20) + xbf_bytes + (1u << 20);
  bool use_bf16x = (ws_size >= need);

  hipLaunchKernelGGL(cvt_w1_kernel, dim3(128), dim3(256), 0, stream, W1, W1s);

  if (use_bf16x){
    unsigned short* xbf = (unsigned short*)((char*)d_ws + (1u << 20));
    float* ctxp = (float*)((char*)d_ws + (1u << 20) + xbf_bytes);
    hipLaunchKernelGGL(scores_kernel,          dim3(2048), dim3(512), 0, stream, x, W1s, b1, w2, scorep, xbf);
    hipLaunchKernelGGL(softmax_kernel,         dim3(64),   dim3(256), 0, stream, scorep, wout);
    hipLaunchKernelGGL(ctx_partial_bf16_kernel,dim3(512),  dim3(512), 0, stream, xbf, wout, ctxp);
    hipLaunchKernelGGL(ctx_reduce_kernel,      dim3(128),  dim3(256), 0, stream, ctxp, ctx);
  } else {
    float* ctxp = (float*)d_ws;                        // reuse W1s region (dead by then)
    hipLaunchKernelGGL(scores_kernel,          dim3(2048), dim3(512), 0, stream, x, W1s, b1, w2, scorep, (unsigned short*)nullptr);
    hipLaunchKernelGGL(softmax_kernel,         dim3(64),   dim3(256), 0, stream, scorep, wout);
    hipLaunchKernelGGL(ctx_partial_kernel,     dim3(512),  dim3(512), 0, stream, x, wout, ctxp);
    hipLaunchKernelGGL(ctx_reduce_kernel,      dim3(128),  dim3(256), 0, stream, ctxp, ctx);
  }
}